// Round 1
// 230.253 us; speedup vs baseline: 1.0204x; 1.0204x over previous
//
#include <hip/hip_runtime.h>
#include <math.h>

#define BB 8
#define LL 4096
#define HH 1024
#define SS 32
#define SEPID 102
#define NROWS 256   // B*S
#define TOK 32
#define SPLITK 8
#define KSLICE (HH / SPLITK)  // 128

// ---------------------------------------------------------------------------
// Kernel 1: per-batch prep + sums zeroing.
// blockIdx.y == 0: find SEP positions (sorted) -> spos_g, masked counts via
// block scan -> cnts. blockIdx.y in 1..8: zero a slice of sums.
// int4-vectorized ids/mask scans (4096 ints in 4 iters of int4 per 256 thr).
// ---------------------------------------------------------------------------
__global__ __launch_bounds__(256) void prep_kernel(
    const int* __restrict__ ids, const int* __restrict__ mask,
    float* __restrict__ cnts, int* __restrict__ spos_g,
    float* __restrict__ sums) {
  int b = blockIdx.x;
  int by = blockIdx.y;
  int tid = threadIdx.x;
  if (by > 0) {
    int z = b * 8 + (by - 1);
    float4 zero = make_float4(0.f, 0.f, 0.f, 0.f);
    float4* p = (float4*)sums + (size_t)z * 1024;
#pragma unroll
    for (int i = 0; i < 4; i++) p[tid + i * 256] = zero;
    return;
  }
  __shared__ int spos_raw[SS];
  __shared__ int spos[SS];
  __shared__ int nsep;
  __shared__ int excl_s[257];
  __shared__ int wtot[4];
  if (tid == 0) nsep = 0;
  if (tid < SS) spos_raw[tid] = LL - 1;
  __syncthreads();
  const int* idb = ids + (size_t)b * LL;
  const int* mb  = mask + (size_t)b * LL;

  const int4* id4 = (const int4*)idb;
#pragma unroll
  for (int it = 0; it < 4; it++) {
    int t4 = tid + it * 256;
    int4 w = id4[t4];
    if (w.x == SEPID) { int s = atomicAdd(&nsep, 1); if (s < SS) spos_raw[s] = t4 * 4 + 0; }
    if (w.y == SEPID) { int s = atomicAdd(&nsep, 1); if (s < SS) spos_raw[s] = t4 * 4 + 1; }
    if (w.z == SEPID) { int s = atomicAdd(&nsep, 1); if (s < SS) spos_raw[s] = t4 * 4 + 2; }
    if (w.w == SEPID) { int s = atomicAdd(&nsep, 1); if (s < SS) spos_raw[s] = t4 * 4 + 3; }
  }
  __syncthreads();
  if (tid < SS) {
    int p = spos_raw[tid];
    int rank = 0;
    for (int j = 0; j < SS; j++) {
      int q = spos_raw[j];
      rank += (q < p) || (q == p && j < tid);
    }
    spos[rank] = p;
  }

  // masked-count exclusive scan: each thread sums 16 masks (4x int4).
  const int4* m4 = (const int4*)mb;
  int local = 0;
#pragma unroll
  for (int i = 0; i < 4; i++) {
    int4 w = m4[tid * 4 + i];
    local += w.x + w.y + w.z + w.w;
  }
  int lane = tid & 63, wave = tid >> 6;
  int v = local;
#pragma unroll
  for (int off = 1; off < 64; off <<= 1) {
    int n = __shfl_up(v, off, 64);
    if (lane >= off) v += n;
  }
  if (lane == 63) wtot[wave] = v;
  __syncthreads();
  int woff = 0;
  for (int w = 0; w < wave; w++) woff += wtot[w];
  excl_s[tid] = woff + v - local;
  if (tid == 0) excl_s[256] = wtot[0] + wtot[1] + wtot[2] + wtot[3];
  __syncthreads();

  if (tid < SS) {
    spos_g[b * SS + tid] = spos[tid];
    int st = (tid == 0) ? 0 : spos[tid - 1];
    int ed = spos[tid];
    int pa = st, pb = ed + 1;
    int ca = excl_s[pa >> 4];
    for (int i = pa & ~15; i < pa; i++) ca += mb[i];
    int cb = excl_s[pb >> 4];
    for (int i = pb & ~15; i < pb; i++) cb += mb[i];
    cnts[b * SS + tid] = (float)max(cb - ca, 1);
  }
}

// ---------------------------------------------------------------------------
// Kernel 2: segment sums. Block = 32-token chunk (1024 blocks = 4 blocks/CU,
// 16 waves/CU for latency hiding). Codes from binary search of the 32 sorted
// SEP positions. Group-of-4 double-buffered register prefetch keeps 4
// outstanding 16B loads/thread. Per-group fast path: when all 4 tokens are
// same-segment / no-SEP / masked-live (the overwhelmingly common case, ~97%
// of groups), skip the per-token decode entirely -> 16 pure v_add.
// ---------------------------------------------------------------------------
__device__ __forceinline__ void flush_seg(float* __restrict__ sums, int b,
                                          int seg, int tid, const float4& acc) {
  if (seg >= 0) {
    float* p = sums + ((size_t)(b * SS + seg)) * HH + tid * 4;
    atomicAdd(p + 0, acc.x);
    atomicAdd(p + 1, acc.y);
    atomicAdd(p + 2, acc.z);
    atomicAdd(p + 3, acc.w);
  }
}

__global__ __launch_bounds__(256, 4) void segsum_kernel(
    const float4* __restrict__ seq, const int* __restrict__ mask,
    const int* __restrict__ spos_g, float* __restrict__ sums) {
  const int chunks = LL / TOK;  // 128
  int b = blockIdx.x / chunks;
  int c = blockIdx.x % chunks;
  int t0 = c * TOK;
  int tid = threadIdx.x;
  __shared__ int sposs[SS];
  __shared__ int scode[TOK];
  if (tid < SS) sposs[tid] = spos_g[b * SS + tid];
  __syncthreads();
  if (t0 > sposs[SS - 1]) return;  // whole chunk after last SEP
  if (tid < TOK) {
    int t = t0 + tid;
    int lo = 0, hi = SS;
    while (lo < hi) {
      int mid = (lo + hi) >> 1;
      if (sposs[mid] < t) lo = mid + 1; else hi = mid;
    }
    int issep = (lo < SS && sposs[lo] == t) ? 1 : 0;
    int r = lo;
    int m = mask[(size_t)b * LL + t];
    int live = (issep || r < SS) ? 1 : 0;
    scode[tid] = ((r << 1) | issep) | ((m && live) ? 0x100 : 0);
  }
  __syncthreads();
  float4 acc = make_float4(0.f, 0.f, 0.f, 0.f);
  int curseg = -1;
  const int rs = HH / 4;
  const float4* rowbase = seq + (size_t)(b * LL + t0) * rs + tid;
  float4 cur[4], nxt[4];
#pragma unroll
  for (int j = 0; j < 4; j++) cur[j] = rowbase[(size_t)j * rs];
  for (int g = 0; g < TOK / 4; g++) {
    int tb = g * 4;
    if (g < TOK / 4 - 1) {
#pragma unroll
      for (int j = 0; j < 4; j++) nxt[j] = rowbase[(size_t)(tb + 4 + j) * rs];
    }
    int4 cd4 = *(const int4*)&scode[tb];
    bool fast = (cd4.x == cd4.y) & (cd4.x == cd4.z) & (cd4.x == cd4.w) &
                ((cd4.x & 1) == 0) & ((cd4.x & 0x100) != 0);
    if (fast) {
      int r = (cd4.x >> 1) & 0x3F;
      if (r != curseg) {
        flush_seg(sums, b, curseg, tid, acc);
        curseg = r;
        acc = make_float4(0.f, 0.f, 0.f, 0.f);
      }
      float4 s01, s23;
      s01.x = cur[0].x + cur[1].x; s01.y = cur[0].y + cur[1].y;
      s01.z = cur[0].z + cur[1].z; s01.w = cur[0].w + cur[1].w;
      s23.x = cur[2].x + cur[3].x; s23.y = cur[2].y + cur[3].y;
      s23.z = cur[2].z + cur[3].z; s23.w = cur[2].w + cur[3].w;
      acc.x += s01.x + s23.x; acc.y += s01.y + s23.y;
      acc.z += s01.z + s23.z; acc.w += s01.w + s23.w;
    } else {
#pragma unroll
      for (int j = 0; j < 4; j++) {
        int cd = scode[tb + j];
        int r = (cd >> 1) & 0x3F;
        int issep = cd & 1;
        float mf = (cd & 0x100) ? 1.f : 0.f;
        float4 v = cur[j];
        v.x *= mf; v.y *= mf; v.z *= mf; v.w *= mf;
        if (issep) {
          if (curseg != r) {
            flush_seg(sums, b, curseg, tid, acc);
            acc = make_float4(0.f, 0.f, 0.f, 0.f);
          }
          acc.x += v.x; acc.y += v.y; acc.z += v.z; acc.w += v.w;
          flush_seg(sums, b, r, tid, acc);
          if (r + 1 < SS) { curseg = r + 1; acc = v; }
          else { curseg = -1; acc = make_float4(0.f, 0.f, 0.f, 0.f); }
        } else {
          int sg = (r < SS) ? r : -1;
          if (sg != curseg) {
            flush_seg(sums, b, curseg, tid, acc);
            curseg = sg;
            acc = make_float4(0.f, 0.f, 0.f, 0.f);
          }
          acc.x += v.x; acc.y += v.y; acc.z += v.z; acc.w += v.w;
        }
      }
    }
#pragma unroll
    for (int j = 0; j < 4; j++) cur[j] = nxt[j];
  }
  flush_seg(sums, b, curseg, tid, acc);
}

// ---------------------------------------------------------------------------
// Kernel 3: split-K GEMM on raw sums (row scaling deferred to final).
// 64x64 tile, 4x4 microtile, k-major LDS, b128 reads. Software-pipelined
// global->reg staging: step k+1's loads issue before step k's FMA phase,
// so HBM/L2 latency hides under the FMAs. Partials, no atomics.
// ---------------------------------------------------------------------------
__global__ __launch_bounds__(256) void gemm1_kernel(
    const float* __restrict__ sums, const float* __restrict__ W1,
    float* __restrict__ h1p) {
  __shared__ float As[32][68];
  __shared__ float Bs[32][68];
  int bj = blockIdx.x;
  int bi = blockIdx.y;
  int bz = blockIdx.z;
  int tid = threadIdx.x;
  int r0 = bi * 64, c0 = bj * 64, kb = bz * KSLICE;

  int ai = tid >> 3;
  int af = tid & 7;
  int bk = tid >> 4;
  int bj4 = tid & 15;
  int tx = tid & 15, ty = tid >> 4;

  float acc[4][4];
#pragma unroll
  for (int i = 0; i < 4; i++)
#pragma unroll
    for (int j = 0; j < 4; j++) acc[i][j] = 0.f;

  const float* aptr0 = &sums[(size_t)(r0 + ai) * HH + af * 4];
  const float* aptr1 = aptr0 + (size_t)32 * HH;
  const float* bptr0 = &W1[(size_t)bk * HH + c0 + bj4 * 4];
  const float* bptr1 = bptr0 + (size_t)16 * HH;

  float4 a0 = *(const float4*)(aptr0 + kb);
  float4 a1 = *(const float4*)(aptr1 + kb);
  float4 b0 = *(const float4*)(bptr0 + (size_t)kb * HH);
  float4 b1 = *(const float4*)(bptr1 + (size_t)kb * HH);

#pragma unroll
  for (int ks = 0; ks < KSLICE / 32; ks++) {
    if (ks) __syncthreads();
    As[af * 4 + 0][ai] = a0.x;
    As[af * 4 + 1][ai] = a0.y;
    As[af * 4 + 2][ai] = a0.z;
    As[af * 4 + 3][ai] = a0.w;
    As[af * 4 + 0][ai + 32] = a1.x;
    As[af * 4 + 1][ai + 32] = a1.y;
    As[af * 4 + 2][ai + 32] = a1.z;
    As[af * 4 + 3][ai + 32] = a1.w;
    *(float4*)&Bs[bk][bj4 * 4] = b0;
    *(float4*)&Bs[bk + 16][bj4 * 4] = b1;
    // prefetch next k-step (clamped on last iter -> redundant L2-hot reload)
    int kn = kb + (ks + 1 < KSLICE / 32 ? (ks + 1) * 32 : ks * 32);
    float4 na0 = *(const float4*)(aptr0 + kn);
    float4 na1 = *(const float4*)(aptr1 + kn);
    float4 nb0 = *(const float4*)(bptr0 + (size_t)kn * HH);
    float4 nb1 = *(const float4*)(bptr1 + (size_t)kn * HH);
    __syncthreads();
#pragma unroll
    for (int kk = 0; kk < 32; kk++) {
      float4 a = *(const float4*)&As[kk][ty * 4];
      float4 b = *(const float4*)&Bs[kk][tx * 4];
      acc[0][0] += a.x * b.x; acc[0][1] += a.x * b.y;
      acc[0][2] += a.x * b.z; acc[0][3] += a.x * b.w;
      acc[1][0] += a.y * b.x; acc[1][1] += a.y * b.y;
      acc[1][2] += a.y * b.z; acc[1][3] += a.y * b.w;
      acc[2][0] += a.z * b.x; acc[2][1] += a.z * b.y;
      acc[2][2] += a.z * b.z; acc[2][3] += a.z * b.w;
      acc[3][0] += a.w * b.x; acc[3][1] += a.w * b.y;
      acc[3][2] += a.w * b.z; acc[3][3] += a.w * b.w;
    }
    a0 = na0; a1 = na1; b0 = nb0; b1 = nb1;
  }
#pragma unroll
  for (int dr = 0; dr < 4; dr++) {
    float4 o = make_float4(acc[dr][0], acc[dr][1], acc[dr][2], acc[dr][3]);
    *(float4*)&h1p[((size_t)bz * NROWS + r0 + ty * 4 + dr) * HH + c0 + tx * 4] = o;
  }
}

// ---------------------------------------------------------------------------
// Kernel 4: sum 8 partials, scale by 1/cnt, + b1 -> LN -> GELU -> @W2 + b2.
// ---------------------------------------------------------------------------
__global__ __launch_bounds__(256) void final_kernel(
    const float* __restrict__ h1p, const float* __restrict__ cnts,
    const float* __restrict__ b1, const float* __restrict__ ln_g,
    const float* __restrict__ ln_b, const float* __restrict__ W2,
    const float* __restrict__ b2, float* __restrict__ out) {
  int r = blockIdx.x;
  int tid = threadIdx.x;
  float4 x = make_float4(0.f, 0.f, 0.f, 0.f);
#pragma unroll
  for (int sl = 0; sl < SPLITK; sl++) {
    float4 p = ((const float4*)(h1p + ((size_t)sl * NROWS + r) * HH))[tid];
    x.x += p.x; x.y += p.y; x.z += p.z; x.w += p.w;
  }
  float invr = 1.0f / cnts[r];
  float4 bb1 = ((const float4*)b1)[tid];
  x.x = x.x * invr + bb1.x;
  x.y = x.y * invr + bb1.y;
  x.z = x.z * invr + bb1.z;
  x.w = x.w * invr + bb1.w;
  float s = x.x + x.y + x.z + x.w;
  float sq = x.x * x.x + x.y * x.y + x.z * x.z + x.w * x.w;
  __shared__ float redA[4], redB[4];
#pragma unroll
  for (int off = 32; off >= 1; off >>= 1) {
    s += __shfl_down(s, off, 64);
    sq += __shfl_down(sq, off, 64);
  }
  int wave = tid >> 6, lane = tid & 63;
  if (lane == 0) { redA[wave] = s; redB[wave] = sq; }
  __syncthreads();
  float ts = redA[0] + redA[1] + redA[2] + redA[3];
  float tq = redB[0] + redB[1] + redB[2] + redB[3];
  float mean = ts * (1.0f / HH);
  float var = tq * (1.0f / HH) - mean * mean;
  float rinv = rsqrtf(var + 1e-5f);
  float4 g4 = ((const float4*)ln_g)[tid];
  float4 bb4 = ((const float4*)ln_b)[tid];
  float4 w20 = ((const float4*)W2)[tid * 2];
  float4 w21 = ((const float4*)W2)[tid * 2 + 1];
  float xs[4] = {x.x, x.y, x.z, x.w};
  float gs[4] = {g4.x, g4.y, g4.z, g4.w};
  float bs[4] = {bb4.x, bb4.y, bb4.z, bb4.w};
  float w0[4] = {w20.x, w20.z, w21.x, w21.z};
  float w1[4] = {w20.y, w20.w, w21.y, w21.w};
  float o0 = 0.f, o1 = 0.f;
#pragma unroll
  for (int j = 0; j < 4; j++) {
    float y = (xs[j] - mean) * rinv * gs[j] + bs[j];
    float gel = 0.5f * y * (1.0f + erff(y * 0.70710678118654752440f));
    o0 += gel * w0[j];
    o1 += gel * w1[j];
  }
#pragma unroll
  for (int off = 32; off >= 1; off >>= 1) {
    o0 += __shfl_down(o0, off, 64);
    o1 += __shfl_down(o1, off, 64);
  }
  __syncthreads();
  if (lane == 0) { redA[wave] = o0; redB[wave] = o1; }
  __syncthreads();
  if (tid == 0) {
    out[(size_t)r * 2 + 0] = redA[0] + redA[1] + redA[2] + redA[3] + b2[0];
    out[(size_t)r * 2 + 1] = redB[0] + redB[1] + redB[2] + redB[3] + b2[1];
  }
}

// ---------------------------------------------------------------------------
extern "C" void kernel_launch(void* const* d_in, const int* in_sizes, int n_in,
                              void* d_out, int out_size, void* d_ws, size_t ws_size,
                              hipStream_t stream) {
  (void)in_sizes; (void)n_in; (void)out_size; (void)ws_size;
  const float* seq  = (const float*)d_in[0];
  const int*   ids  = (const int*)d_in[1];
  const int*   mask = (const int*)d_in[2];
  const float* W1   = (const float*)d_in[3];
  const float* b1   = (const float*)d_in[4];
  const float* ln_g = (const float*)d_in[5];
  const float* ln_b = (const float*)d_in[6];
  const float* W2   = (const float*)d_in[7];
  const float* b2   = (const float*)d_in[8];
  float* out = (float*)d_out;

  char* ws = (char*)d_ws;
  float* sums = (float*)ws;                         // 1 MB (zeroed by prep)
  float* h1p  = (float*)(ws + (1 << 20));           // 8 MB partials
  float* cnts = (float*)(ws + (9 << 20));           // 1 KB
  int*   spos = (int*)(ws + (9 << 20) + 4096);      // 1 KB

  dim3 gp(BB, 9);
  prep_kernel<<<gp, 256, 0, stream>>>(ids, mask, cnts, spos, sums);
  segsum_kernel<<<BB * (LL / TOK), 256, 0, stream>>>(
      (const float4*)seq, mask, spos, sums);
  dim3 g1(16, 4, SPLITK);
  gemm1_kernel<<<g1, 256, 0, stream>>>(sums, W1, h1p);
  final_kernel<<<NROWS, 256, 0, stream>>>(h1p, cnts, b1, ln_g, ln_b, W2, b2, out);
}